// Round 6
// baseline (276.723 us; speedup 1.0000x reference)
//
#include <hip/hip_runtime.h>
#include <hip/hip_bf16.h>

#define N_NODES 50000
#define N_EDGES 800000
#define NPAD    50048          // 782 * 64
#define IN_DIM  100
#define HID     128
#define BN_EPS  1e-5f

#define BSHIFT  6
#define BUCKS   782            // ceil(50000 / 64)
#define BSTRIDE 2048           // fixed slots per bucket in ebuf (mean 1024, 32 sigma)
#define BCAP    2048           // LDS edge capacity per bucket

typedef unsigned int uint;
typedef unsigned short u16;
typedef __attribute__((ext_vector_type(8))) unsigned short us8;
typedef __attribute__((ext_vector_type(8))) short s8;      // bf16 MFMA frag
typedef __attribute__((ext_vector_type(4))) float f4;

__device__ __forceinline__ u16 f2bf(float f) {
    uint u = __builtin_bit_cast(uint, f);
    uint r = (u + 0x7FFFu + ((u >> 16) & 1u)) >> 16;   // RNE
    return (u16)r;
}
__device__ __forceinline__ uint pack2(float a, float b) {
    return (uint)f2bf(a) | ((uint)f2bf(b) << 16);
}
__device__ __forceinline__ float bflo(uint p) { return __builtin_bit_cast(float, p << 16); }
__device__ __forceinline__ float bfhi(uint p) { return __builtin_bit_cast(float, p & 0xFFFF0000u); }

// ---------------------------------------------------------------------------
// Bucketed edge organization: fixed per-bucket strides; per-block LDS
// histogram -> one global reservation per (block,bucket) -> LDS-cursor scatter.
// ---------------------------------------------------------------------------
__global__ void init_cursor(int* __restrict__ bcursor) {
    int b = blockIdx.x * 256 + threadIdx.x;
    if (b < BUCKS) bcursor[b] = b * BSTRIDE;
}

__global__ __launch_bounds__(1024) void bucket_scatter_blk(
    const int* __restrict__ src, const int* __restrict__ dst,
    int* __restrict__ bcursor, uint* __restrict__ ebuf) {
    __shared__ int h[BUCKS];    // counts, then local cursors
    __shared__ int gb[BUCKS];   // this block's reserved base per bucket
    int t = threadIdx.x;
    for (int i = t; i < BUCKS; i += 1024) h[i] = 0;
    __syncthreads();
    int base = blockIdx.x * 8192;
    int myb[8]; uint myv[8];
    #pragma unroll
    for (int r = 0; r < 8; ++r) {
        int e = base + r * 1024 + t;
        int b = -1; uint val = 0;
        if (e < N_EDGES) {
            int d = dst[e];
            b = d >> BSHIFT;
            val = (uint)src[e] | ((uint)(d & 63) << 16);
            atomicAdd(&h[b], 1);
        }
        myb[r] = b; myv[r] = val;
    }
    __syncthreads();
    for (int i = t; i < BUCKS; i += 1024) {
        int c = h[i];
        gb[i] = c ? atomicAdd(&bcursor[i], c) : 0;
        h[i] = 0;   // reuse as local cursor
    }
    __syncthreads();
    #pragma unroll
    for (int r = 0; r < 8; ++r) {
        int b = myb[r];
        if (b >= 0) {
            int pos = gb[b] + atomicAdd(&h[b], 1);
            ebuf[pos] = myv[r];
        }
    }
}

// ---------------------------------------------------------------------------
// Casts to bf16
// ---------------------------------------------------------------------------
__global__ void cast_x_kernel(const float* __restrict__ x, u16* __restrict__ xb) {
    int idx = blockIdx.x * blockDim.x + threadIdx.x;
    if (idx >= NPAD * 128) return;
    int row = idx >> 7, k = idx & 127;
    float v = (row < N_NODES && k < IN_DIM) ? x[row * IN_DIM + k] : 0.f;
    xb[idx] = f2bf(v);
}

// weights: fp32 [Ksrc][128] -> bf16 transposed [128 n][128 k], zero-padded k
__global__ void cast_w_kernel(const float* __restrict__ W_l0, const float* __restrict__ W_r0,
                              const float* __restrict__ W_l1, const float* __restrict__ W_r1,
                              u16* __restrict__ d) {
    int w = blockIdx.y;
    const float* s = (w == 0) ? W_l0 : (w == 1) ? W_r0 : (w == 2) ? W_l1 : W_r1;
    int Ks = (w < 2) ? IN_DIM : HID;
    int idx = blockIdx.x * 256 + threadIdx.x;   // 0..16383
    int n = idx >> 7, k = idx & 127;
    float v = (k < Ks) ? s[k * 128 + n] : 0.f;
    d[w * 16384 + idx] = f2bf(v);
}

// ---------------------------------------------------------------------------
// Fused per-bucket kernel: LDS CSR -> gather-mean into LDS A1 tile ->
// stage root rows into LDS A2 tile (aliases edge bufs) -> dual MFMA GEMM.
//   out[64 x 128] = mean_agg @ WtL^T + X[rows] @ WtR^T + bias
// 512 threads (8 waves); wave -> 16 rows x 64 cols.
// A tiles stride 136 u16 (272 B) and Bls stride 40 u16 (80 B): 2-way max
// bank aliasing on b128 LDS ops (free per m136).
// ---------------------------------------------------------------------------
__global__ __launch_bounds__(512) void agg_gemm(
    const uint* __restrict__ ebuf, const int* __restrict__ bcursor,
    const u16* __restrict__ X,
    const u16* __restrict__ WtL, const u16* __restrict__ WtR,
    const float* __restrict__ bias, float* __restrict__ out) {
    __shared__ u16 Aagg[64][136];
    __shared__ __align__(16) char r2[64 * 136 * 2];   // Ax  |  eL+srcL
    __shared__ u16 Bls[128][40];
    __shared__ int cnt[64], ro[65], cur[64];

    u16 (*Ax)[136] = (u16(*)[136])r2;
    uint* eL  = (uint*)r2;                    // 8192 B
    u16*  srcL = (u16*)(r2 + BCAP * 4);       // 4096 B  (12288 <= 17408)

    int b = blockIdx.x;
    int t = threadIdx.x;
    int row0 = b * 64;
    int wave = t >> 6, lane = t & 63;
    int quad = lane >> 4, sub = lane & 15, l16 = lane & 15;

    // ---- bucket-local CSR in LDS
    int n = bcursor[b] - b * BSTRIDE;
    if (n > BCAP) n = BCAP;   // statistically unreachable
    if (t < 64) cnt[t] = 0;
    __syncthreads();
    for (int i = t; i < n; i += 512) {
        uint p = ebuf[b * BSTRIDE + i];
        eL[i] = p;
        atomicAdd(&cnt[p >> 16], 1);
    }
    __syncthreads();
    if (t < 64) {
        int v = cnt[t];
        int s = v;
        #pragma unroll
        for (int off = 1; off < 64; off <<= 1) {
            int u = __shfl_up(s, off, 64);
            if (t >= off) s += u;
        }
        ro[t] = s - v;
        cur[t] = s - v;
        if (t == 63) ro[64] = s;
    }
    __syncthreads();
    for (int i = t; i < n; i += 512) {
        uint p = eL[i];
        int pos = atomicAdd(&cur[p >> 16], 1);
        srcL[pos] = (u16)(p & 0xFFFFu);
    }
    __syncthreads();

    // ---- gather-mean into Aagg (wave per 8 nodes, quad-parallel edges)
    #pragma unroll
    for (int ni = 0; ni < 8; ++ni) {
        int nl = wave * 8 + ni;
        int node = row0 + nl;
        if (node >= N_NODES) {           // zero-fill padding rows (wave-uniform)
            if (quad == 0) {
                uint4 z = make_uint4(0, 0, 0, 0);
                *(uint4*)&Aagg[nl][sub * 8] = z;
            }
            continue;
        }
        int rb = ro[nl], re = ro[nl + 1];
        float a0 = 0.f, a1 = 0.f, a2 = 0.f, a3 = 0.f;
        float a4 = 0.f, a5 = 0.f, a6 = 0.f, a7 = 0.f;
        int e = rb;
        for (; e + 16 <= re; e += 16) {   // 4 independent loads in flight
            int s0 = srcL[e + quad];
            int s1 = srcL[e + 4 + quad];
            int s2 = srcL[e + 8 + quad];
            int s3 = srcL[e + 12 + quad];
            uint4 v0 = ((const uint4*)(X + (size_t)s0 * 128))[sub];
            uint4 v1 = ((const uint4*)(X + (size_t)s1 * 128))[sub];
            uint4 v2 = ((const uint4*)(X + (size_t)s2 * 128))[sub];
            uint4 v3 = ((const uint4*)(X + (size_t)s3 * 128))[sub];
            a0 += (bflo(v0.x) + bflo(v1.x)) + (bflo(v2.x) + bflo(v3.x));
            a1 += (bfhi(v0.x) + bfhi(v1.x)) + (bfhi(v2.x) + bfhi(v3.x));
            a2 += (bflo(v0.y) + bflo(v1.y)) + (bflo(v2.y) + bflo(v3.y));
            a3 += (bfhi(v0.y) + bfhi(v1.y)) + (bfhi(v2.y) + bfhi(v3.y));
            a4 += (bflo(v0.z) + bflo(v1.z)) + (bflo(v2.z) + bflo(v3.z));
            a5 += (bfhi(v0.z) + bfhi(v1.z)) + (bfhi(v2.z) + bfhi(v3.z));
            a6 += (bflo(v0.w) + bflo(v1.w)) + (bflo(v2.w) + bflo(v3.w));
            a7 += (bfhi(v0.w) + bfhi(v1.w)) + (bfhi(v2.w) + bfhi(v3.w));
        }
        for (; e + 8 <= re; e += 8) {
            int s0 = srcL[e + quad];
            int s1 = srcL[e + 4 + quad];
            uint4 v0 = ((const uint4*)(X + (size_t)s0 * 128))[sub];
            uint4 v1 = ((const uint4*)(X + (size_t)s1 * 128))[sub];
            a0 += bflo(v0.x) + bflo(v1.x);
            a1 += bfhi(v0.x) + bfhi(v1.x);
            a2 += bflo(v0.y) + bflo(v1.y);
            a3 += bfhi(v0.y) + bfhi(v1.y);
            a4 += bflo(v0.z) + bflo(v1.z);
            a5 += bfhi(v0.z) + bfhi(v1.z);
            a6 += bflo(v0.w) + bflo(v1.w);
            a7 += bfhi(v0.w) + bfhi(v1.w);
        }
        for (; e < re; e += 4) {
            int ee = e + quad;
            if (ee < re) {
                int s0 = srcL[ee];
                uint4 v0 = ((const uint4*)(X + (size_t)s0 * 128))[sub];
                a0 += bflo(v0.x); a1 += bfhi(v0.x);
                a2 += bflo(v0.y); a3 += bfhi(v0.y);
                a4 += bflo(v0.z); a5 += bfhi(v0.z);
                a6 += bflo(v0.w); a7 += bfhi(v0.w);
            }
        }
        #pragma unroll
        for (int m = 16; m <= 32; m <<= 1) {
            a0 += __shfl_xor(a0, m, 64); a1 += __shfl_xor(a1, m, 64);
            a2 += __shfl_xor(a2, m, 64); a3 += __shfl_xor(a3, m, 64);
            a4 += __shfl_xor(a4, m, 64); a5 += __shfl_xor(a5, m, 64);
            a6 += __shfl_xor(a6, m, 64); a7 += __shfl_xor(a7, m, 64);
        }
        if (quad == 0) {
            float inv = 1.0f / fmaxf((float)(re - rb), 1.0f);
            uint4 o;
            o.x = pack2(a0 * inv, a1 * inv);
            o.y = pack2(a2 * inv, a3 * inv);
            o.z = pack2(a4 * inv, a5 * inv);
            o.w = pack2(a6 * inv, a7 * inv);
            *(uint4*)&Aagg[nl][sub * 8] = o;
        }
    }
    __syncthreads();   // all gathers done (srcL free), Aagg complete

    // ---- stage root rows into Ax (overwrites eL/srcL)
    #pragma unroll
    for (int p = 0; p < 2; ++p) {
        int idx = p * 512 + t;        // 0..1023
        int r = idx >> 4, c = idx & 15;
        *(us8*)&Ax[r][c * 8] = *(const us8*)(X + (size_t)(row0 + r) * 128 + c * 8);
    }
    __syncthreads();

    // ---- dual GEMM: wave -> rows rm..rm+15, cols cn..cn+63
    int rm = (wave & 3) * 16;
    int cn = (wave >> 2) * 64;
    f4 acc[4];
    #pragma unroll
    for (int j = 0; j < 4; j++) acc[j] = (f4)0.f;

    #pragma unroll
    for (int phase = 0; phase < 2; ++phase) {
        const u16 (*A)[136] = phase ? (const u16(*)[136])Ax : (const u16(*)[136])Aagg;
        const u16* Wt = phase ? WtR : WtL;
        #pragma unroll
        for (int k0 = 0; k0 < 128; k0 += 32) {
            __syncthreads();
            {   // stage B k-chunk: 128 n x 32 k, one pass of 512 threads
                int nn = t >> 2, c = t & 3;
                *(us8*)&Bls[nn][c * 8] = *(const us8*)(Wt + nn * 128 + k0 + c * 8);
            }
            __syncthreads();
            s8 af = *(const s8*)&A[rm + l16][k0 + quad * 8];
            #pragma unroll
            for (int nt = 0; nt < 4; ++nt) {
                s8 bfr = *(const s8*)&Bls[cn + nt * 16 + l16][quad * 8];
                acc[nt] = __builtin_amdgcn_mfma_f32_16x16x32_bf16(af, bfr, acc[nt], 0, 0, 0);
            }
        }
    }

    // ---- epilogue (C/D: col=lane&15, row=quad*4+reg)
    #pragma unroll
    for (int nt = 0; nt < 4; ++nt) {
        int col = cn + nt * 16 + l16;
        float bv = bias[col];
        #pragma unroll
        for (int r = 0; r < 4; ++r) {
            int row = row0 + rm + quad * 4 + r;
            if (row < N_NODES)
                out[(size_t)row * 128 + col] = acc[nt][r] + bv;
        }
    }
}

// ---------------------------------------------------------------------------
// BatchNorm stats: float4 reads, LDS tree, 8 atomics per block
// ---------------------------------------------------------------------------
__global__ void stats_kernel(const float* __restrict__ h, float* __restrict__ stats, int M) {
    __shared__ float l1[256 * 4], l2[256 * 4];
    int t = threadIdx.x;             // 256
    int tg = t >> 5, c = t & 31;
    float s1x = 0.f, s1y = 0.f, s1z = 0.f, s1w = 0.f;
    float s2x = 0.f, s2y = 0.f, s2z = 0.f, s2w = 0.f;
    for (int n = blockIdx.x * 8 + tg; n < M; n += gridDim.x * 8) {
        float4 v = ((const float4*)(h + (size_t)n * 128))[c];
        s1x += v.x; s1y += v.y; s1z += v.z; s1w += v.w;
        s2x = fmaf(v.x, v.x, s2x); s2y = fmaf(v.y, v.y, s2y);
        s2z = fmaf(v.z, v.z, s2z); s2w = fmaf(v.w, v.w, s2w);
    }
    l1[t * 4 + 0] = s1x; l1[t * 4 + 1] = s1y; l1[t * 4 + 2] = s1z; l1[t * 4 + 3] = s1w;
    l2[t * 4 + 0] = s2x; l2[t * 4 + 1] = s2y; l2[t * 4 + 2] = s2z; l2[t * 4 + 3] = s2w;
    __syncthreads();
    #pragma unroll
    for (int stride = 128; stride >= 64; stride >>= 1) {
        if (t < stride) {
            #pragma unroll
            for (int j = 0; j < 4; j++) {
                l1[t * 4 + j] += l1[(t + stride) * 4 + j];
                l2[t * 4 + j] += l2[(t + stride) * 4 + j];
            }
        }
        __syncthreads();
    }
    if (t < 32) {
        #pragma unroll
        for (int j = 0; j < 4; j++) {
            float v1 = l1[t * 4 + j] + l1[(t + 32) * 4 + j];
            float v2 = l2[t * 4 + j] + l2[(t + 32) * 4 + j];
            atomicAdd(&stats[t * 4 + j], v1);
            atomicAdd(&stats[128 + t * 4 + j], v2);
        }
    }
}

// BN(+ReLU)+cast to bf16, finalize inlined (layer-0 -> layer-1 handoff)
__global__ void bn_relu_cast_kernel(const float* __restrict__ h,
                                    const float* __restrict__ stats,
                                    const float* __restrict__ gamma,
                                    const float* __restrict__ beta,
                                    u16* __restrict__ hb, float inv_n, int total4) {
    __shared__ float ss[256];
    int t = threadIdx.x;
    if (t < 128) {
        float mean = stats[t] * inv_n;
        float var = stats[128 + t] * inv_n - mean * mean;
        float inv = 1.0f / sqrtf(var + BN_EPS);
        float sc = gamma[t] * inv;
        ss[t] = sc;
        ss[128 + t] = beta[t] - mean * sc;
    }
    __syncthreads();
    for (int i = blockIdx.x * 256 + t; i < total4; i += gridDim.x * 256) {
        int cg = i & 31;
        float4 v = ((const float4*)h)[i];
        float4 sc = *(const float4*)&ss[cg * 4];
        float4 sh = *(const float4*)&ss[128 + cg * 4];
        float r0 = fmaxf(fmaf(v.x, sc.x, sh.x), 0.f);
        float r1 = fmaxf(fmaf(v.y, sc.y, sh.y), 0.f);
        float r2 = fmaxf(fmaf(v.z, sc.z, sh.z), 0.f);
        float r3 = fmaxf(fmaf(v.w, sc.w, sh.w), 0.f);
        uint2 o;
        o.x = pack2(r0, r1);
        o.y = pack2(r2, r3);
        ((uint2*)hb)[i] = o;
    }
}

// zero-fill padding rows of hb (50000..50047) so layer-1 root staging is clean
__global__ void pad_hb_kernel(u16* __restrict__ hb) {
    int i = blockIdx.x * 256 + threadIdx.x;   // (NPAD-N_NODES)*128 = 6144
    if (i < (NPAD - N_NODES) * 128) hb[N_NODES * 128 + i] = 0;
}

// final BN, fp32 in-place on d_out, finalize inlined
__global__ void bn_apply_kernel(float* __restrict__ h,
                                const float* __restrict__ stats,
                                const float* __restrict__ gamma,
                                const float* __restrict__ beta,
                                float inv_n, int total4) {
    __shared__ float ss[256];
    int t = threadIdx.x;
    if (t < 128) {
        float mean = stats[t] * inv_n;
        float var = stats[128 + t] * inv_n - mean * mean;
        float inv = 1.0f / sqrtf(var + BN_EPS);
        float sc = gamma[t] * inv;
        ss[t] = sc;
        ss[128 + t] = beta[t] - mean * sc;
    }
    __syncthreads();
    for (int i = blockIdx.x * 256 + t; i < total4; i += gridDim.x * 256) {
        int cg = i & 31;
        float4 v = ((float4*)h)[i];
        float4 sc = *(const float4*)&ss[cg * 4];
        float4 sh = *(const float4*)&ss[128 + cg * 4];
        v.x = fmaf(v.x, sc.x, sh.x);
        v.y = fmaf(v.y, sc.y, sh.y);
        v.z = fmaf(v.z, sc.z, sh.z);
        v.w = fmaf(v.w, sc.w, sh.w);
        ((float4*)h)[i] = v;
    }
}

// ---------------------------------------------------------------------------
extern "C" void kernel_launch(void* const* d_in, const int* in_sizes, int n_in,
                              void* d_out, int out_size, void* d_ws, size_t ws_size,
                              hipStream_t stream) {
    const float* x      = (const float*)d_in[0];
    const int*   ei     = (const int*)d_in[1];
    const float* W_l0   = (const float*)d_in[2];
    const float* b_l0   = (const float*)d_in[3];
    const float* W_r0   = (const float*)d_in[4];
    const float* gamma0 = (const float*)d_in[5];
    const float* beta0  = (const float*)d_in[6];
    const float* W_l1   = (const float*)d_in[7];
    const float* b_l1   = (const float*)d_in[8];
    const float* W_r1   = (const float*)d_in[9];
    const float* gamma1 = (const float*)d_in[10];
    const float* beta1  = (const float*)d_in[11];

    const int* src = ei;
    const int* dst = ei + N_EDGES;

    char* w = (char*)d_ws;
    auto alloc = [&](size_t bytes) {
        void* p = (void*)w;
        w += (bytes + 255) & ~(size_t)255;
        return p;
    };
    // zero-init span: stats0, stats1 contiguous
    char* zbase    = w;
    float* stats0  = (float*)alloc(sizeof(float) * 256);
    float* stats1  = (float*)alloc(sizeof(float) * 256);
    size_t zbytes  = (size_t)(w - zbase);

    int* bcursor   = (int*)alloc(sizeof(int) * BUCKS);
    uint* ebuf     = (uint*)alloc(sizeof(uint) * BUCKS * BSTRIDE);
    u16* xb        = (u16*)alloc(sizeof(u16) * (size_t)NPAD * 128);
    u16* hb        = (u16*)alloc(sizeof(u16) * (size_t)NPAD * 128);
    u16* Wt        = (u16*)alloc(sizeof(u16) * 4 * 16384);
    float* outp    = (float*)d_out;   // fp32 scratch for layer-0 pre-BN

    hipMemsetAsync(zbase, 0, zbytes, stream);

    const float inv_n = 1.0f / (float)N_NODES;
    const int total4 = N_NODES * HID / 4;

    // bucketed edge organization + casts
    init_cursor<<<(BUCKS + 255) / 256, 256, 0, stream>>>(bcursor);
    bucket_scatter_blk<<<(N_EDGES + 8191) / 8192, 1024, 0, stream>>>(src, dst, bcursor, ebuf);
    cast_x_kernel<<<(NPAD * 128 + 255) / 256, 256, 0, stream>>>(x, xb);
    cast_w_kernel<<<dim3(64, 4), 256, 0, stream>>>(W_l0, W_r0, W_l1, W_r1, Wt);

    // Layer 0 (fused agg+gemm)
    agg_gemm<<<BUCKS, 512, 0, stream>>>(ebuf, bcursor, xb, Wt, Wt + 16384, b_l0, outp);
    stats_kernel<<<128, 256, 0, stream>>>(outp, stats0, N_NODES);
    bn_relu_cast_kernel<<<2048, 256, 0, stream>>>(outp, stats0, gamma0, beta0, hb, inv_n, total4);
    pad_hb_kernel<<<24, 256, 0, stream>>>(hb);

    // Layer 1 (fused agg+gemm)
    agg_gemm<<<BUCKS, 512, 0, stream>>>(ebuf, bcursor, hb, Wt + 2 * 16384, Wt + 3 * 16384, b_l1, outp);
    stats_kernel<<<128, 256, 0, stream>>>(outp, stats1, N_NODES);
    bn_apply_kernel<<<2048, 256, 0, stream>>>(outp, stats1, gamma1, beta1, inv_n, total4);
}

// Round 7
// 253.529 us; speedup vs baseline: 1.0915x; 1.0915x over previous
//
#include <hip/hip_runtime.h>
#include <hip/hip_bf16.h>

#define N_NODES 50000
#define N_EDGES 800000
#define NPAD    50048          // 782 * 64
#define IN_DIM  100
#define HID     128
#define BN_EPS  1e-5f

#define BSHIFT  6
#define BUCKS   782            // ceil(50000 / 64)
#define BSTRIDE 2048           // fixed slots per bucket in ebuf (mean 1024, 32 sigma)
#define BCAP    2048           // LDS edge capacity per bucket
#define NSLICE  16             // stats atomic slices (depth 782/16 ~ 49 per address)

typedef unsigned int uint;
typedef unsigned short u16;
typedef __attribute__((ext_vector_type(8))) unsigned short us8;
typedef __attribute__((ext_vector_type(8))) short s8;      // bf16 MFMA frag
typedef __attribute__((ext_vector_type(4))) float f4;

__device__ __forceinline__ u16 f2bf(float f) {
    uint u = __builtin_bit_cast(uint, f);
    uint r = (u + 0x7FFFu + ((u >> 16) & 1u)) >> 16;   // RNE
    return (u16)r;
}
__device__ __forceinline__ uint pack2(float a, float b) {
    return (uint)f2bf(a) | ((uint)f2bf(b) << 16);
}
__device__ __forceinline__ float bflo(uint p) { return __builtin_bit_cast(float, p << 16); }
__device__ __forceinline__ float bfhi(uint p) { return __builtin_bit_cast(float, p & 0xFFFF0000u); }

// ---------------------------------------------------------------------------
// Bucketed edge organization: fixed per-bucket strides; per-block LDS
// histogram -> one global reservation per (block,bucket) -> LDS-cursor scatter.
// ---------------------------------------------------------------------------
__global__ void init_cursor(int* __restrict__ bcursor) {
    int b = blockIdx.x * 256 + threadIdx.x;
    if (b < BUCKS) bcursor[b] = b * BSTRIDE;
}

__global__ __launch_bounds__(1024) void bucket_scatter_blk(
    const int* __restrict__ src, const int* __restrict__ dst,
    int* __restrict__ bcursor, uint* __restrict__ ebuf) {
    __shared__ int h[BUCKS];    // counts, then local cursors
    __shared__ int gb[BUCKS];   // this block's reserved base per bucket
    int t = threadIdx.x;
    for (int i = t; i < BUCKS; i += 1024) h[i] = 0;
    __syncthreads();
    int base = blockIdx.x * 8192;
    int myb[8]; uint myv[8];
    #pragma unroll
    for (int r = 0; r < 8; ++r) {
        int e = base + r * 1024 + t;
        int b = -1; uint val = 0;
        if (e < N_EDGES) {
            int d = dst[e];
            b = d >> BSHIFT;
            val = (uint)src[e] | ((uint)(d & 63) << 16);
            atomicAdd(&h[b], 1);
        }
        myb[r] = b; myv[r] = val;
    }
    __syncthreads();
    for (int i = t; i < BUCKS; i += 1024) {
        int c = h[i];
        gb[i] = c ? atomicAdd(&bcursor[i], c) : 0;
        h[i] = 0;   // reuse as local cursor
    }
    __syncthreads();
    #pragma unroll
    for (int r = 0; r < 8; ++r) {
        int b = myb[r];
        if (b >= 0) {
            int pos = gb[b] + atomicAdd(&h[b], 1);
            ebuf[pos] = myv[r];
        }
    }
}

// ---------------------------------------------------------------------------
// Casts to bf16
// ---------------------------------------------------------------------------
__global__ void cast_x_kernel(const float* __restrict__ x, u16* __restrict__ xb) {
    int idx = blockIdx.x * blockDim.x + threadIdx.x;
    if (idx >= NPAD * 128) return;
    int row = idx >> 7, k = idx & 127;
    float v = (row < N_NODES && k < IN_DIM) ? x[row * IN_DIM + k] : 0.f;
    xb[idx] = f2bf(v);
}

// weights: fp32 [Ksrc][128] -> bf16 transposed [128 n][128 k], zero-padded k
__global__ void cast_w_kernel(const float* __restrict__ W_l0, const float* __restrict__ W_r0,
                              const float* __restrict__ W_l1, const float* __restrict__ W_r1,
                              u16* __restrict__ d) {
    int w = blockIdx.y;
    const float* s = (w == 0) ? W_l0 : (w == 1) ? W_r0 : (w == 2) ? W_l1 : W_r1;
    int Ks = (w < 2) ? IN_DIM : HID;
    int idx = blockIdx.x * 256 + threadIdx.x;   // 0..16383
    int n = idx >> 7, k = idx & 127;
    float v = (k < Ks) ? s[k * 128 + n] : 0.f;
    d[w * 16384 + idx] = f2bf(v);
}

// ---------------------------------------------------------------------------
// Fused per-bucket kernel v2: LDS CSR -> gather-mean into LDS A-tile ->
// dual MFMA GEMM with B (and root-A) fragments loaded DIRECT from global
// (Wt pre-transposed, L2-resident; no Bls/Ax staging, no in-loop barriers).
// Epilogue: store out + BN partial stats (block -> LDS tile -> 16-slice
// global atomics; pad rows excluded).
// LDS ~31.5 KB -> 4 blocks/CU (32 waves = HW cap).
// ---------------------------------------------------------------------------
__global__ __launch_bounds__(512) void agg_gemm(
    const uint* __restrict__ ebuf, const int* __restrict__ bcursor,
    const u16* __restrict__ X,
    const u16* __restrict__ WtL, const u16* __restrict__ WtR,
    const float* __restrict__ bias, float* __restrict__ out,
    float* __restrict__ gstats) {
    __shared__ u16 Aagg[64][136];        // 17408 B (272 B row = 16B-aligned)
    __shared__ uint eL[BCAP];            // 8192 B
    __shared__ u16 srcL[BCAP];           // 4096 B
    __shared__ int cnt[64], ro[65], cur[64];
    __shared__ float s1L[128], s2L[128];

    int b = blockIdx.x;
    int t = threadIdx.x;
    int row0 = b * 64;
    int wave = t >> 6, lane = t & 63;
    int quad = lane >> 4, sub = lane & 15, l16 = lane & 15;

    // ---- bucket-local CSR in LDS
    int n = bcursor[b] - b * BSTRIDE;
    if (n > BCAP) n = BCAP;   // statistically unreachable
    if (t < 64) cnt[t] = 0;
    if (t < 128) { s1L[t] = 0.f; s2L[t] = 0.f; }
    __syncthreads();
    for (int i = t; i < n; i += 512) {
        uint p = ebuf[b * BSTRIDE + i];
        eL[i] = p;
        atomicAdd(&cnt[p >> 16], 1);
    }
    __syncthreads();
    if (t < 64) {
        int v = cnt[t];
        int s = v;
        #pragma unroll
        for (int off = 1; off < 64; off <<= 1) {
            int u = __shfl_up(s, off, 64);
            if (t >= off) s += u;
        }
        ro[t] = s - v;
        cur[t] = s - v;
        if (t == 63) ro[64] = s;
    }
    __syncthreads();
    for (int i = t; i < n; i += 512) {
        uint p = eL[i];
        int pos = atomicAdd(&cur[p >> 16], 1);
        srcL[pos] = (u16)(p & 0xFFFFu);
    }
    __syncthreads();

    // ---- gather-mean into Aagg (wave per 8 nodes, quad-parallel edges)
    #pragma unroll
    for (int ni = 0; ni < 8; ++ni) {
        int nl = wave * 8 + ni;
        int node = row0 + nl;
        if (node >= N_NODES) {           // zero-fill padding rows (wave-uniform)
            if (quad == 0) {
                uint4 z = make_uint4(0, 0, 0, 0);
                *(uint4*)&Aagg[nl][sub * 8] = z;
            }
            continue;
        }
        int rb = ro[nl], re = ro[nl + 1];
        float a0 = 0.f, a1 = 0.f, a2 = 0.f, a3 = 0.f;
        float a4 = 0.f, a5 = 0.f, a6 = 0.f, a7 = 0.f;
        int e = rb;
        for (; e + 16 <= re; e += 16) {   // 4 independent loads in flight
            int s0 = srcL[e + quad];
            int s1 = srcL[e + 4 + quad];
            int s2 = srcL[e + 8 + quad];
            int s3 = srcL[e + 12 + quad];
            uint4 v0 = ((const uint4*)(X + (size_t)s0 * 128))[sub];
            uint4 v1 = ((const uint4*)(X + (size_t)s1 * 128))[sub];
            uint4 v2 = ((const uint4*)(X + (size_t)s2 * 128))[sub];
            uint4 v3 = ((const uint4*)(X + (size_t)s3 * 128))[sub];
            a0 += (bflo(v0.x) + bflo(v1.x)) + (bflo(v2.x) + bflo(v3.x));
            a1 += (bfhi(v0.x) + bfhi(v1.x)) + (bfhi(v2.x) + bfhi(v3.x));
            a2 += (bflo(v0.y) + bflo(v1.y)) + (bflo(v2.y) + bflo(v3.y));
            a3 += (bfhi(v0.y) + bfhi(v1.y)) + (bfhi(v2.y) + bfhi(v3.y));
            a4 += (bflo(v0.z) + bflo(v1.z)) + (bflo(v2.z) + bflo(v3.z));
            a5 += (bfhi(v0.z) + bfhi(v1.z)) + (bfhi(v2.z) + bfhi(v3.z));
            a6 += (bflo(v0.w) + bflo(v1.w)) + (bflo(v2.w) + bflo(v3.w));
            a7 += (bfhi(v0.w) + bfhi(v1.w)) + (bfhi(v2.w) + bfhi(v3.w));
        }
        for (; e + 8 <= re; e += 8) {
            int s0 = srcL[e + quad];
            int s1 = srcL[e + 4 + quad];
            uint4 v0 = ((const uint4*)(X + (size_t)s0 * 128))[sub];
            uint4 v1 = ((const uint4*)(X + (size_t)s1 * 128))[sub];
            a0 += bflo(v0.x) + bflo(v1.x);
            a1 += bfhi(v0.x) + bfhi(v1.x);
            a2 += bflo(v0.y) + bflo(v1.y);
            a3 += bfhi(v0.y) + bfhi(v1.y);
            a4 += bflo(v0.z) + bflo(v1.z);
            a5 += bfhi(v0.z) + bfhi(v1.z);
            a6 += bflo(v0.w) + bflo(v1.w);
            a7 += bfhi(v0.w) + bfhi(v1.w);
        }
        for (; e < re; e += 4) {
            int ee = e + quad;
            if (ee < re) {
                int s0 = srcL[ee];
                uint4 v0 = ((const uint4*)(X + (size_t)s0 * 128))[sub];
                a0 += bflo(v0.x); a1 += bfhi(v0.x);
                a2 += bflo(v0.y); a3 += bfhi(v0.y);
                a4 += bflo(v0.z); a5 += bfhi(v0.z);
                a6 += bflo(v0.w); a7 += bfhi(v0.w);
            }
        }
        #pragma unroll
        for (int m = 16; m <= 32; m <<= 1) {
            a0 += __shfl_xor(a0, m, 64); a1 += __shfl_xor(a1, m, 64);
            a2 += __shfl_xor(a2, m, 64); a3 += __shfl_xor(a3, m, 64);
            a4 += __shfl_xor(a4, m, 64); a5 += __shfl_xor(a5, m, 64);
            a6 += __shfl_xor(a6, m, 64); a7 += __shfl_xor(a7, m, 64);
        }
        if (quad == 0) {
            float inv = 1.0f / fmaxf((float)(re - rb), 1.0f);
            uint4 o;
            o.x = pack2(a0 * inv, a1 * inv);
            o.y = pack2(a2 * inv, a3 * inv);
            o.z = pack2(a4 * inv, a5 * inv);
            o.w = pack2(a6 * inv, a7 * inv);
            *(uint4*)&Aagg[nl][sub * 8] = o;
        }
    }
    __syncthreads();   // Aagg complete

    // ---- dual GEMM: wave -> rows rm..rm+15, cols cn..cn+63
    int rm = (wave & 3) * 16;
    int cn = (wave >> 2) * 64;
    f4 acc[4];
    #pragma unroll
    for (int j = 0; j < 4; j++) acc[j] = (f4)0.f;

    // phase 0: Aagg (LDS) x WtL (global, L2-hot)
    #pragma unroll
    for (int k0 = 0; k0 < 128; k0 += 32) {
        s8 af = *(const s8*)&Aagg[rm + l16][k0 + quad * 8];
        #pragma unroll
        for (int nt = 0; nt < 4; ++nt) {
            s8 bfr = *(const s8*)(WtL + (cn + nt * 16 + l16) * 128 + k0 + quad * 8);
            acc[nt] = __builtin_amdgcn_mfma_f32_16x16x32_bf16(af, bfr, acc[nt], 0, 0, 0);
        }
    }
    // phase 1: root rows of X (global) x WtR (global)
    #pragma unroll
    for (int k0 = 0; k0 < 128; k0 += 32) {
        s8 af = *(const s8*)(X + (size_t)(row0 + rm + l16) * 128 + k0 + quad * 8);
        #pragma unroll
        for (int nt = 0; nt < 4; ++nt) {
            s8 bfr = *(const s8*)(WtR + (cn + nt * 16 + l16) * 128 + k0 + quad * 8);
            acc[nt] = __builtin_amdgcn_mfma_f32_16x16x32_bf16(af, bfr, acc[nt], 0, 0, 0);
        }
    }

    // ---- epilogue: store + BN partial stats (C/D: col=lane&15, row=quad*4+reg)
    #pragma unroll
    for (int nt = 0; nt < 4; ++nt) {
        int col = cn + nt * 16 + l16;
        float bv = bias[col];
        float s1 = 0.f, s2 = 0.f;
        #pragma unroll
        for (int r = 0; r < 4; ++r) {
            int row = row0 + rm + quad * 4 + r;
            if (row < N_NODES) {
                float v = acc[nt][r] + bv;
                out[(size_t)row * 128 + col] = v;
                s1 += v;
                s2 = fmaf(v, v, s2);
            }
        }
        s1 += __shfl_xor(s1, 16, 64); s2 += __shfl_xor(s2, 16, 64);
        s1 += __shfl_xor(s1, 32, 64); s2 += __shfl_xor(s2, 32, 64);
        if (quad == 0) {
            atomicAdd(&s1L[col], s1);
            atomicAdd(&s2L[col], s2);
        }
    }
    __syncthreads();
    int slice = b & (NSLICE - 1);
    if (t < 128) {
        atomicAdd(&gstats[slice * 256 + t], s1L[t]);
        atomicAdd(&gstats[slice * 256 + 128 + t], s2L[t]);
    }
}

// ---------------------------------------------------------------------------
// BN(+ReLU)+cast to bf16, finalize (16-slice sum) inlined; also zero-fills
// hb padding rows. (layer-0 -> layer-1 handoff)
// ---------------------------------------------------------------------------
__global__ void bn_relu_cast_kernel(const float* __restrict__ h,
                                    const float* __restrict__ gstats,
                                    const float* __restrict__ gamma,
                                    const float* __restrict__ beta,
                                    u16* __restrict__ hb, float inv_n, int total4) {
    __shared__ float ss[256];
    int t = threadIdx.x;
    if (t < 128) {
        float m = 0.f, q = 0.f;
        #pragma unroll
        for (int s = 0; s < NSLICE; ++s) {
            m += gstats[s * 256 + t];
            q += gstats[s * 256 + 128 + t];
        }
        float mean = m * inv_n;
        float var = q * inv_n - mean * mean;
        float inv = 1.0f / sqrtf(var + BN_EPS);
        float sc = gamma[t] * inv;
        ss[t] = sc;
        ss[128 + t] = beta[t] - mean * sc;
    }
    __syncthreads();
    int gid = blockIdx.x * 256 + t;
    if (gid < 768) {   // zero hb padding rows 50000..50047 (6144 u16 = 768 uint4)
        ((uint4*)(hb + (size_t)N_NODES * 128))[gid] = make_uint4(0, 0, 0, 0);
    }
    for (int i = gid; i < total4; i += gridDim.x * 256) {
        int cg = i & 31;
        float4 v = ((const float4*)h)[i];
        float4 sc = *(const float4*)&ss[cg * 4];
        float4 sh = *(const float4*)&ss[128 + cg * 4];
        float r0 = fmaxf(fmaf(v.x, sc.x, sh.x), 0.f);
        float r1 = fmaxf(fmaf(v.y, sc.y, sh.y), 0.f);
        float r2 = fmaxf(fmaf(v.z, sc.z, sh.z), 0.f);
        float r3 = fmaxf(fmaf(v.w, sc.w, sh.w), 0.f);
        uint2 o;
        o.x = pack2(r0, r1);
        o.y = pack2(r2, r3);
        ((uint2*)hb)[i] = o;
    }
}

// final BN, fp32 in-place on d_out, finalize (16-slice sum) inlined
__global__ void bn_apply_kernel(float* __restrict__ h,
                                const float* __restrict__ gstats,
                                const float* __restrict__ gamma,
                                const float* __restrict__ beta,
                                float inv_n, int total4) {
    __shared__ float ss[256];
    int t = threadIdx.x;
    if (t < 128) {
        float m = 0.f, q = 0.f;
        #pragma unroll
        for (int s = 0; s < NSLICE; ++s) {
            m += gstats[s * 256 + t];
            q += gstats[s * 256 + 128 + t];
        }
        float mean = m * inv_n;
        float var = q * inv_n - mean * mean;
        float inv = 1.0f / sqrtf(var + BN_EPS);
        float sc = gamma[t] * inv;
        ss[t] = sc;
        ss[128 + t] = beta[t] - mean * sc;
    }
    __syncthreads();
    for (int i = blockIdx.x * 256 + t; i < total4; i += gridDim.x * 256) {
        int cg = i & 31;
        float4 v = ((float4*)h)[i];
        float4 sc = *(const float4*)&ss[cg * 4];
        float4 sh = *(const float4*)&ss[128 + cg * 4];
        v.x = fmaf(v.x, sc.x, sh.x);
        v.y = fmaf(v.y, sc.y, sh.y);
        v.z = fmaf(v.z, sc.z, sh.z);
        v.w = fmaf(v.w, sc.w, sh.w);
        ((float4*)h)[i] = v;
    }
}

// ---------------------------------------------------------------------------
extern "C" void kernel_launch(void* const* d_in, const int* in_sizes, int n_in,
                              void* d_out, int out_size, void* d_ws, size_t ws_size,
                              hipStream_t stream) {
    const float* x      = (const float*)d_in[0];
    const int*   ei     = (const int*)d_in[1];
    const float* W_l0   = (const float*)d_in[2];
    const float* b_l0   = (const float*)d_in[3];
    const float* W_r0   = (const float*)d_in[4];
    const float* gamma0 = (const float*)d_in[5];
    const float* beta0  = (const float*)d_in[6];
    const float* W_l1   = (const float*)d_in[7];
    const float* b_l1   = (const float*)d_in[8];
    const float* W_r1   = (const float*)d_in[9];
    const float* gamma1 = (const float*)d_in[10];
    const float* beta1  = (const float*)d_in[11];

    const int* src = ei;
    const int* dst = ei + N_EDGES;

    char* w = (char*)d_ws;
    auto alloc = [&](size_t bytes) {
        void* p = (void*)w;
        w += (bytes + 255) & ~(size_t)255;
        return p;
    };
    // zero-init span: gstats0, gstats1 contiguous (16 slices x 256 floats each)
    char* zbase    = w;
    float* gstats0 = (float*)alloc(sizeof(float) * NSLICE * 256);
    float* gstats1 = (float*)alloc(sizeof(float) * NSLICE * 256);
    size_t zbytes  = (size_t)(w - zbase);

    int* bcursor   = (int*)alloc(sizeof(int) * BUCKS);
    uint* ebuf     = (uint*)alloc(sizeof(uint) * BUCKS * BSTRIDE);
    u16* xb        = (u16*)alloc(sizeof(u16) * (size_t)NPAD * 128);
    u16* hb        = (u16*)alloc(sizeof(u16) * (size_t)NPAD * 128);
    u16* Wt        = (u16*)alloc(sizeof(u16) * 4 * 16384);
    float* outp    = (float*)d_out;   // fp32 scratch for layer-0 pre-BN

    hipMemsetAsync(zbase, 0, zbytes, stream);

    const float inv_n = 1.0f / (float)N_NODES;
    const int total4 = N_NODES * HID / 4;

    // bucketed edge organization + casts
    init_cursor<<<(BUCKS + 255) / 256, 256, 0, stream>>>(bcursor);
    bucket_scatter_blk<<<(N_EDGES + 8191) / 8192, 1024, 0, stream>>>(src, dst, bcursor, ebuf);
    cast_x_kernel<<<(NPAD * 128 + 255) / 256, 256, 0, stream>>>(x, xb);
    cast_w_kernel<<<dim3(64, 4), 256, 0, stream>>>(W_l0, W_r0, W_l1, W_r1, Wt);

    // Layer 0 (fused agg+gemm+stats)
    agg_gemm<<<BUCKS, 512, 0, stream>>>(ebuf, bcursor, xb, Wt, Wt + 16384, b_l0, outp, gstats0);
    bn_relu_cast_kernel<<<2048, 256, 0, stream>>>(outp, gstats0, gamma0, beta0, hb, inv_n, total4);

    // Layer 1 (fused agg+gemm+stats)
    agg_gemm<<<BUCKS, 512, 0, stream>>>(ebuf, bcursor, hb, Wt + 2 * 16384, Wt + 3 * 16384, b_l1, outp, gstats1);
    bn_apply_kernel<<<2048, 256, 0, stream>>>(outp, gstats1, gamma1, beta1, inv_n, total4);
}

// Round 8
// 232.899 us; speedup vs baseline: 1.1882x; 1.0886x over previous
//
#include <hip/hip_runtime.h>
#include <hip/hip_bf16.h>

#define N_NODES 50000
#define N_EDGES 800000
#define NPAD    50048          // 782 * 64
#define IN_DIM  100
#define HID     128
#define BN_EPS  1e-5f

#define BSHIFT  6
#define BUCKS   782            // ceil(50000 / 64)
#define BSTRIDE 2048           // fixed slots per bucket in ebuf (mean 1024, 32 sigma)
#define BCAP    2048           // LDS edge capacity per bucket
#define NSLICE  16             // stats atomic slices

typedef unsigned int uint;
typedef unsigned short u16;
typedef __attribute__((ext_vector_type(8))) unsigned short us8;
typedef __attribute__((ext_vector_type(8))) short s8;       // bf16 MFMA frag
typedef __attribute__((ext_vector_type(16))) float f16v;    // 32x32 accumulator

__device__ __forceinline__ u16 f2bf(float f) {
    uint u = __builtin_bit_cast(uint, f);
    uint r = (u + 0x7FFFu + ((u >> 16) & 1u)) >> 16;   // RNE
    return (u16)r;
}
__device__ __forceinline__ uint pack2(float a, float b) {
    return (uint)f2bf(a) | ((uint)f2bf(b) << 16);
}
__device__ __forceinline__ float bflo(uint p) { return __builtin_bit_cast(float, p << 16); }
__device__ __forceinline__ float bfhi(uint p) { return __builtin_bit_cast(float, p & 0xFFFF0000u); }

// ---------------------------------------------------------------------------
// Bucketed edge organization (unchanged from round 5/7 — measured fast)
// ---------------------------------------------------------------------------
__global__ void init_cursor(int* __restrict__ bcursor) {
    int b = blockIdx.x * 256 + threadIdx.x;
    if (b < BUCKS) bcursor[b] = b * BSTRIDE;
}

__global__ __launch_bounds__(1024) void bucket_scatter_blk(
    const int* __restrict__ src, const int* __restrict__ dst,
    int* __restrict__ bcursor, uint* __restrict__ ebuf) {
    __shared__ int h[BUCKS];
    __shared__ int gb[BUCKS];
    int t = threadIdx.x;
    for (int i = t; i < BUCKS; i += 1024) h[i] = 0;
    __syncthreads();
    int base = blockIdx.x * 8192;
    int myb[8]; uint myv[8];
    #pragma unroll
    for (int r = 0; r < 8; ++r) {
        int e = base + r * 1024 + t;
        int b = -1; uint val = 0;
        if (e < N_EDGES) {
            int d = dst[e];
            b = d >> BSHIFT;
            val = (uint)src[e] | ((uint)(d & 63) << 16);
            atomicAdd(&h[b], 1);
        }
        myb[r] = b; myv[r] = val;
    }
    __syncthreads();
    for (int i = t; i < BUCKS; i += 1024) {
        int c = h[i];
        gb[i] = c ? atomicAdd(&bcursor[i], c) : 0;
        h[i] = 0;
    }
    __syncthreads();
    #pragma unroll
    for (int r = 0; r < 8; ++r) {
        int b = myb[r];
        if (b >= 0) {
            int pos = gb[b] + atomicAdd(&h[b], 1);
            ebuf[pos] = myv[r];
        }
    }
}

// ---------------------------------------------------------------------------
// Casts to bf16
// ---------------------------------------------------------------------------
__global__ void cast_x_kernel(const float* __restrict__ x, u16* __restrict__ xb) {
    int idx = blockIdx.x * blockDim.x + threadIdx.x;
    if (idx >= NPAD * 128) return;
    int row = idx >> 7, k = idx & 127;
    float v = (row < N_NODES && k < IN_DIM) ? x[row * IN_DIM + k] : 0.f;
    xb[idx] = f2bf(v);
}

__global__ void cast_w_kernel(const float* __restrict__ W_l0, const float* __restrict__ W_r0,
                              const float* __restrict__ W_l1, const float* __restrict__ W_r1,
                              u16* __restrict__ d) {
    int w = blockIdx.y;
    const float* s = (w == 0) ? W_l0 : (w == 1) ? W_r0 : (w == 2) ? W_l1 : W_r1;
    int Ks = (w < 2) ? IN_DIM : HID;
    int idx = blockIdx.x * 256 + threadIdx.x;   // 0..16383
    int n = idx >> 7, k = idx & 127;
    float v = (k < Ks) ? s[k * 128 + n] : 0.f;
    d[w * 16384 + idx] = f2bf(v);
}

// ---------------------------------------------------------------------------
// Fused per-bucket kernel v3: LDS CSR -> gather-mean -> 32x32x16 MFMA GEMM
// (B and root-A frags direct from global, 1-deep prefetch pipeline).
// WRITE_BF16=1: store h as raw bf16 into outb (layer 0); else fp32 into outf.
// Epilogue accumulates exact fp32 BN stats -> 16-slice global atomics.
// ---------------------------------------------------------------------------
template <int WRITE_BF16>
__global__ __launch_bounds__(512) void agg_gemm(
    const uint* __restrict__ ebuf, const int* __restrict__ bcursor,
    const u16* __restrict__ X,
    const u16* __restrict__ WtL, const u16* __restrict__ WtR,
    const float* __restrict__ bias,
    float* __restrict__ outf, u16* __restrict__ outb,
    float* __restrict__ gstats) {
    __shared__ u16 Aagg[64][136];        // 17408 B
    __shared__ uint eL[BCAP];            // 8192 B
    __shared__ u16 srcL[BCAP];           // 4096 B
    __shared__ int cnt[64], ro[65], cur[64];
    __shared__ float s1L[128], s2L[128];

    int b = blockIdx.x;
    int t = threadIdx.x;
    int row0 = b * 64;
    int wave = t >> 6, lane = t & 63;
    int quad = lane >> 4, sub = lane & 15;

    // ---- bucket-local CSR in LDS
    int n = bcursor[b] - b * BSTRIDE;
    if (n > BCAP) n = BCAP;
    if (t < 64) cnt[t] = 0;
    if (t < 128) { s1L[t] = 0.f; s2L[t] = 0.f; }
    __syncthreads();
    for (int i = t; i < n; i += 512) {
        uint p = ebuf[b * BSTRIDE + i];
        eL[i] = p;
        atomicAdd(&cnt[p >> 16], 1);
    }
    __syncthreads();
    if (t < 64) {
        int v = cnt[t];
        int s = v;
        #pragma unroll
        for (int off = 1; off < 64; off <<= 1) {
            int u = __shfl_up(s, off, 64);
            if (t >= off) s += u;
        }
        ro[t] = s - v;
        cur[t] = s - v;
        if (t == 63) ro[64] = s;
    }
    __syncthreads();
    for (int i = t; i < n; i += 512) {
        uint p = eL[i];
        int pos = atomicAdd(&cur[p >> 16], 1);
        srcL[pos] = (u16)(p & 0xFFFFu);
    }
    __syncthreads();

    // ---- gather-mean into Aagg (wave per 8 nodes, quad-parallel edges)
    #pragma unroll
    for (int ni = 0; ni < 8; ++ni) {
        int nl = wave * 8 + ni;
        int node = row0 + nl;
        if (node >= N_NODES) {
            if (quad == 0) *(uint4*)&Aagg[nl][sub * 8] = make_uint4(0, 0, 0, 0);
            continue;
        }
        int rb = ro[nl], re = ro[nl + 1];
        float a0 = 0.f, a1 = 0.f, a2 = 0.f, a3 = 0.f;
        float a4 = 0.f, a5 = 0.f, a6 = 0.f, a7 = 0.f;
        int e = rb;
        for (; e + 16 <= re; e += 16) {
            int s0 = srcL[e + quad];
            int s1 = srcL[e + 4 + quad];
            int s2 = srcL[e + 8 + quad];
            int s3 = srcL[e + 12 + quad];
            uint4 v0 = ((const uint4*)(X + (size_t)s0 * 128))[sub];
            uint4 v1 = ((const uint4*)(X + (size_t)s1 * 128))[sub];
            uint4 v2 = ((const uint4*)(X + (size_t)s2 * 128))[sub];
            uint4 v3 = ((const uint4*)(X + (size_t)s3 * 128))[sub];
            a0 += (bflo(v0.x) + bflo(v1.x)) + (bflo(v2.x) + bflo(v3.x));
            a1 += (bfhi(v0.x) + bfhi(v1.x)) + (bfhi(v2.x) + bfhi(v3.x));
            a2 += (bflo(v0.y) + bflo(v1.y)) + (bflo(v2.y) + bflo(v3.y));
            a3 += (bfhi(v0.y) + bfhi(v1.y)) + (bfhi(v2.y) + bfhi(v3.y));
            a4 += (bflo(v0.z) + bflo(v1.z)) + (bflo(v2.z) + bflo(v3.z));
            a5 += (bfhi(v0.z) + bfhi(v1.z)) + (bfhi(v2.z) + bfhi(v3.z));
            a6 += (bflo(v0.w) + bflo(v1.w)) + (bflo(v2.w) + bflo(v3.w));
            a7 += (bfhi(v0.w) + bfhi(v1.w)) + (bfhi(v2.w) + bfhi(v3.w));
        }
        for (; e + 8 <= re; e += 8) {
            int s0 = srcL[e + quad];
            int s1 = srcL[e + 4 + quad];
            uint4 v0 = ((const uint4*)(X + (size_t)s0 * 128))[sub];
            uint4 v1 = ((const uint4*)(X + (size_t)s1 * 128))[sub];
            a0 += bflo(v0.x) + bflo(v1.x);
            a1 += bfhi(v0.x) + bfhi(v1.x);
            a2 += bflo(v0.y) + bflo(v1.y);
            a3 += bfhi(v0.y) + bfhi(v1.y);
            a4 += bflo(v0.z) + bflo(v1.z);
            a5 += bfhi(v0.z) + bfhi(v1.z);
            a6 += bflo(v0.w) + bflo(v1.w);
            a7 += bfhi(v0.w) + bfhi(v1.w);
        }
        for (; e < re; e += 4) {
            int ee = e + quad;
            if (ee < re) {
                int s0 = srcL[ee];
                uint4 v0 = ((const uint4*)(X + (size_t)s0 * 128))[sub];
                a0 += bflo(v0.x); a1 += bfhi(v0.x);
                a2 += bflo(v0.y); a3 += bfhi(v0.y);
                a4 += bflo(v0.z); a5 += bfhi(v0.z);
                a6 += bflo(v0.w); a7 += bfhi(v0.w);
            }
        }
        #pragma unroll
        for (int m = 16; m <= 32; m <<= 1) {
            a0 += __shfl_xor(a0, m, 64); a1 += __shfl_xor(a1, m, 64);
            a2 += __shfl_xor(a2, m, 64); a3 += __shfl_xor(a3, m, 64);
            a4 += __shfl_xor(a4, m, 64); a5 += __shfl_xor(a5, m, 64);
            a6 += __shfl_xor(a6, m, 64); a7 += __shfl_xor(a7, m, 64);
        }
        if (quad == 0) {
            float inv = 1.0f / fmaxf((float)(re - rb), 1.0f);
            uint4 o;
            o.x = pack2(a0 * inv, a1 * inv);
            o.y = pack2(a2 * inv, a3 * inv);
            o.z = pack2(a4 * inv, a5 * inv);
            o.w = pack2(a6 * inv, a7 * inv);
            *(uint4*)&Aagg[nl][sub * 8] = o;
        }
    }
    __syncthreads();   // Aagg complete

    // ---- dual GEMM, 32x32x16 MFMA; wave -> rows rm..rm+31, cols cn..cn+31
    int m31 = lane & 31;
    int kh  = lane >> 5;          // k-half: elems k = k0 + kh*8 + j
    int rm = (wave & 1) * 32;
    int cn = (wave >> 1) * 32;
    f16v acc = (f16v)0.f;

    // phase 0: Aagg (LDS) x WtL (global, L2-hot), 1-deep prefetch
    {
        s8 a_nxt = *(const s8*)&Aagg[rm + m31][kh * 8];
        s8 b_nxt = *(const s8*)(WtL + (cn + m31) * 128 + kh * 8);
        #pragma unroll
        for (int ks = 0; ks < 8; ++ks) {
            s8 a_cur = a_nxt, b_cur = b_nxt;
            if (ks < 7) {
                a_nxt = *(const s8*)&Aagg[rm + m31][(ks + 1) * 16 + kh * 8];
                b_nxt = *(const s8*)(WtL + (cn + m31) * 128 + (ks + 1) * 16 + kh * 8);
            }
            acc = __builtin_amdgcn_mfma_f32_32x32x16_bf16(a_cur, b_cur, acc, 0, 0, 0);
        }
    }
    // phase 1: root rows of X (global) x WtR (global)
    {
        const u16* xrow = X + (size_t)(row0 + rm + m31) * 128;
        s8 a_nxt = *(const s8*)(xrow + kh * 8);
        s8 b_nxt = *(const s8*)(WtR + (cn + m31) * 128 + kh * 8);
        #pragma unroll
        for (int ks = 0; ks < 8; ++ks) {
            s8 a_cur = a_nxt, b_cur = b_nxt;
            if (ks < 7) {
                a_nxt = *(const s8*)(xrow + (ks + 1) * 16 + kh * 8);
                b_nxt = *(const s8*)(WtR + (cn + m31) * 128 + (ks + 1) * 16 + kh * 8);
            }
            acc = __builtin_amdgcn_mfma_f32_32x32x16_bf16(a_cur, b_cur, acc, 0, 0, 0);
        }
    }

    // ---- epilogue: store + BN partial stats
    // C/D 32x32: col=lane&31, row=(reg&3)+8*(reg>>2)+4*(lane>>5)  [m74/m101]
    {
        int col = cn + m31;
        float bv = bias[col];
        float s1 = 0.f, s2 = 0.f;
        #pragma unroll
        for (int reg = 0; reg < 16; ++reg) {
            int rowin = (reg & 3) + 8 * (reg >> 2) + 4 * kh;
            int row = row0 + rm + rowin;
            if (row < N_NODES) {
                float v = acc[reg] + bv;
                if (WRITE_BF16)
                    outb[(size_t)row * 128 + col] = f2bf(v);
                else
                    outf[(size_t)row * 128 + col] = v;
                s1 += v;
                s2 = fmaf(v, v, s2);
            }
        }
        s1 += __shfl_xor(s1, 32, 64);
        s2 += __shfl_xor(s2, 32, 64);
        if (lane < 32) {
            atomicAdd(&s1L[col], s1);
            atomicAdd(&s2L[col], s2);
        }
    }
    __syncthreads();
    int slice = b & (NSLICE - 1);
    if (t < 128) {
        atomicAdd(&gstats[slice * 256 + t], s1L[t]);
        atomicAdd(&gstats[slice * 256 + 128 + t], s2L[t]);
    }
}

// ---------------------------------------------------------------------------
// BN(+ReLU) in-place on raw bf16 h (layer-0 -> layer-1 handoff).
// ---------------------------------------------------------------------------
__global__ void bn_relu_inplace(u16* __restrict__ hb,
                                const float* __restrict__ gstats,
                                const float* __restrict__ gamma,
                                const float* __restrict__ beta,
                                float inv_n, int totalv) {   // totalv = N_NODES*16 (uint4s)
    __shared__ float ss[256];
    int t = threadIdx.x;
    if (t < 128) {
        float m = 0.f, q = 0.f;
        #pragma unroll
        for (int s = 0; s < NSLICE; ++s) {
            m += gstats[s * 256 + t];
            q += gstats[s * 256 + 128 + t];
        }
        float mean = m * inv_n;
        float var = q * inv_n - mean * mean;
        float inv = 1.0f / sqrtf(var + BN_EPS);
        float sc = gamma[t] * inv;
        ss[t] = sc;
        ss[128 + t] = beta[t] - mean * sc;
    }
    __syncthreads();
    for (int i = blockIdx.x * 256 + t; i < totalv; i += gridDim.x * 256) {
        int cg = (i & 15) * 8;   // first col of this 8-col group
        uint4 p = ((const uint4*)hb)[i];
        float4 scA = *(const float4*)&ss[cg];
        float4 scB = *(const float4*)&ss[cg + 4];
        float4 shA = *(const float4*)&ss[128 + cg];
        float4 shB = *(const float4*)&ss[128 + cg + 4];
        float r0 = fmaxf(fmaf(bflo(p.x), scA.x, shA.x), 0.f);
        float r1 = fmaxf(fmaf(bfhi(p.x), scA.y, shA.y), 0.f);
        float r2 = fmaxf(fmaf(bflo(p.y), scA.z, shA.z), 0.f);
        float r3 = fmaxf(fmaf(bfhi(p.y), scA.w, shA.w), 0.f);
        float r4 = fmaxf(fmaf(bflo(p.z), scB.x, shB.x), 0.f);
        float r5 = fmaxf(fmaf(bfhi(p.z), scB.y, shB.y), 0.f);
        float r6 = fmaxf(fmaf(bflo(p.w), scB.z, shB.z), 0.f);
        float r7 = fmaxf(fmaf(bfhi(p.w), scB.w, shB.w), 0.f);
        uint4 o;
        o.x = pack2(r0, r1);
        o.y = pack2(r2, r3);
        o.z = pack2(r4, r5);
        o.w = pack2(r6, r7);
        ((uint4*)hb)[i] = o;
    }
}

// final BN, fp32 in-place on d_out
__global__ void bn_apply_kernel(float* __restrict__ h,
                                const float* __restrict__ gstats,
                                const float* __restrict__ gamma,
                                const float* __restrict__ beta,
                                float inv_n, int total4) {
    __shared__ float ss[256];
    int t = threadIdx.x;
    if (t < 128) {
        float m = 0.f, q = 0.f;
        #pragma unroll
        for (int s = 0; s < NSLICE; ++s) {
            m += gstats[s * 256 + t];
            q += gstats[s * 256 + 128 + t];
        }
        float mean = m * inv_n;
        float var = q * inv_n - mean * mean;
        float inv = 1.0f / sqrtf(var + BN_EPS);
        float sc = gamma[t] * inv;
        ss[t] = sc;
        ss[128 + t] = beta[t] - mean * sc;
    }
    __syncthreads();
    for (int i = blockIdx.x * 256 + t; i < total4; i += gridDim.x * 256) {
        int cg = i & 31;
        float4 v = ((float4*)h)[i];
        float4 sc = *(const float4*)&ss[cg * 4];
        float4 sh = *(const float4*)&ss[128 + cg * 4];
        v.x = fmaf(v.x, sc.x, sh.x);
        v.y = fmaf(v.y, sc.y, sh.y);
        v.z = fmaf(v.z, sc.z, sh.z);
        v.w = fmaf(v.w, sc.w, sh.w);
        ((float4*)h)[i] = v;
    }
}

// ---------------------------------------------------------------------------
extern "C" void kernel_launch(void* const* d_in, const int* in_sizes, int n_in,
                              void* d_out, int out_size, void* d_ws, size_t ws_size,
                              hipStream_t stream) {
    const float* x      = (const float*)d_in[0];
    const int*   ei     = (const int*)d_in[1];
    const float* W_l0   = (const float*)d_in[2];
    const float* b_l0   = (const float*)d_in[3];
    const float* W_r0   = (const float*)d_in[4];
    const float* gamma0 = (const float*)d_in[5];
    const float* beta0  = (const float*)d_in[6];
    const float* W_l1   = (const float*)d_in[7];
    const float* b_l1   = (const float*)d_in[8];
    const float* W_r1   = (const float*)d_in[9];
    const float* gamma1 = (const float*)d_in[10];
    const float* beta1  = (const float*)d_in[11];

    const int* src = ei;
    const int* dst = ei + N_EDGES;

    char* w = (char*)d_ws;
    auto alloc = [&](size_t bytes) {
        void* p = (void*)w;
        w += (bytes + 255) & ~(size_t)255;
        return p;
    };
    char* zbase    = w;
    float* gstats0 = (float*)alloc(sizeof(float) * NSLICE * 256);
    float* gstats1 = (float*)alloc(sizeof(float) * NSLICE * 256);
    size_t zbytes  = (size_t)(w - zbase);

    int* bcursor   = (int*)alloc(sizeof(int) * BUCKS);
    uint* ebuf     = (uint*)alloc(sizeof(uint) * BUCKS * BSTRIDE);
    u16* xb        = (u16*)alloc(sizeof(u16) * (size_t)NPAD * 128);
    u16* hb        = (u16*)alloc(sizeof(u16) * (size_t)NPAD * 128);
    u16* Wt        = (u16*)alloc(sizeof(u16) * 4 * 16384);
    float* outp    = (float*)d_out;

    hipMemsetAsync(zbase, 0, zbytes, stream);

    const float inv_n = 1.0f / (float)N_NODES;
    const int total4 = N_NODES * HID / 4;
    const int totalv = N_NODES * HID / 8;

    init_cursor<<<(BUCKS + 255) / 256, 256, 0, stream>>>(bcursor);
    bucket_scatter_blk<<<(N_EDGES + 8191) / 8192, 1024, 0, stream>>>(src, dst, bcursor, ebuf);
    cast_x_kernel<<<(NPAD * 128 + 255) / 256, 256, 0, stream>>>(x, xb);
    cast_w_kernel<<<dim3(64, 4), 256, 0, stream>>>(W_l0, W_r0, W_l1, W_r1, Wt);

    // Layer 0: fused agg+gemm+stats, h -> raw bf16 hb
    agg_gemm<1><<<BUCKS, 512, 0, stream>>>(ebuf, bcursor, xb, Wt, Wt + 16384, b_l0,
                                           nullptr, hb, gstats0);
    bn_relu_inplace<<<1024, 256, 0, stream>>>(hb, gstats0, gamma0, beta0, inv_n, totalv);

    // Layer 1: fused agg+gemm+stats, -> fp32 d_out
    agg_gemm<0><<<BUCKS, 512, 0, stream>>>(ebuf, bcursor, hb, Wt + 2 * 16384, Wt + 3 * 16384,
                                           b_l1, outp, nullptr, gstats1);
    bn_apply_kernel<<<2048, 256, 0, stream>>>(outp, gstats1, gamma1, beta1, inv_n, total4);
}

// Round 9
// 230.324 us; speedup vs baseline: 1.2015x; 1.0112x over previous
//
#include <hip/hip_runtime.h>
#include <hip/hip_bf16.h>

#define N_NODES 50000
#define N_EDGES 800000
#define NPAD    50048          // 782 * 64
#define IN_DIM  100
#define HID     128
#define BN_EPS  1e-5f

#define BSHIFT  6
#define BUCKS   782            // ceil(50000 / 64)
#define BSTRIDE 2048           // fixed slots per bucket in ebuf (mean 1024, 32 sigma)
#define BCAP    2048           // LDS edge capacity per bucket
#define NSLICE  16             // stats atomic slices

typedef unsigned int uint;
typedef unsigned short u16;
typedef __attribute__((ext_vector_type(8))) unsigned short us8;
typedef __attribute__((ext_vector_type(8))) short s8;       // bf16 MFMA frag
typedef __attribute__((ext_vector_type(16))) float f16v;    // 32x32 accumulator

__device__ __forceinline__ u16 f2bf(float f) {
    uint u = __builtin_bit_cast(uint, f);
    uint r = (u + 0x7FFFu + ((u >> 16) & 1u)) >> 16;   // RNE
    return (u16)r;
}
__device__ __forceinline__ uint pack2(float a, float b) {
    return (uint)f2bf(a) | ((uint)f2bf(b) << 16);
}
__device__ __forceinline__ float bflo(uint p) { return __builtin_bit_cast(float, p << 16); }
__device__ __forceinline__ float bfhi(uint p) { return __builtin_bit_cast(float, p & 0xFFFF0000u); }

// ---------------------------------------------------------------------------
// Bucketed edge scatter: bcursor zero-initialized by memset; per-block LDS
// histogram -> one global reservation per (block,bucket) -> LDS-cursor scatter.
// ---------------------------------------------------------------------------
__global__ __launch_bounds__(1024) void bucket_scatter_blk(
    const int* __restrict__ src, const int* __restrict__ dst,
    int* __restrict__ bcursor, uint* __restrict__ ebuf) {
    __shared__ int h[BUCKS];
    __shared__ int gb[BUCKS];
    int t = threadIdx.x;
    for (int i = t; i < BUCKS; i += 1024) h[i] = 0;
    __syncthreads();
    int base = blockIdx.x * 8192;
    int myb[8]; uint myv[8];
    #pragma unroll
    for (int r = 0; r < 8; ++r) {
        int e = base + r * 1024 + t;
        int b = -1; uint val = 0;
        if (e < N_EDGES) {
            int d = dst[e];
            b = d >> BSHIFT;
            val = (uint)src[e] | ((uint)(d & 63) << 16);
            atomicAdd(&h[b], 1);
        }
        myb[r] = b; myv[r] = val;
    }
    __syncthreads();
    for (int i = t; i < BUCKS; i += 1024) {
        int c = h[i];
        gb[i] = c ? (i * BSTRIDE + atomicAdd(&bcursor[i], c)) : 0;
        h[i] = 0;
    }
    __syncthreads();
    #pragma unroll
    for (int r = 0; r < 8; ++r) {
        int b = myb[r];
        if (b >= 0) {
            int pos = gb[b] + atomicAdd(&h[b], 1);
            ebuf[pos] = myv[r];
        }
    }
}

// ---------------------------------------------------------------------------
// One cast kernel: x -> bf16 padded [NPAD][128], then 4 weights -> bf16
// transposed [128 n][128 k] (zero-padded k).
// ---------------------------------------------------------------------------
__global__ void cast_all(const float* __restrict__ x,
                         const float* __restrict__ W_l0, const float* __restrict__ W_r0,
                         const float* __restrict__ W_l1, const float* __restrict__ W_r1,
                         u16* __restrict__ xb, u16* __restrict__ Wt) {
    int idx = blockIdx.x * 256 + threadIdx.x;
    if (idx < NPAD * 128) {
        int row = idx >> 7, k = idx & 127;
        float v = (row < N_NODES && k < IN_DIM) ? x[row * IN_DIM + k] : 0.f;
        xb[idx] = f2bf(v);
        return;
    }
    int i2 = idx - NPAD * 128;
    if (i2 >= 4 * 16384) return;
    int w = i2 >> 14, i3 = i2 & 16383;
    const float* s = (w == 0) ? W_l0 : (w == 1) ? W_r0 : (w == 2) ? W_l1 : W_r1;
    int Ks = (w < 2) ? IN_DIM : HID;
    int n = i3 >> 7, k = i3 & 127;
    float v = (k < Ks) ? s[k * 128 + n] : 0.f;
    Wt[i2] = f2bf(v);
}

// ---------------------------------------------------------------------------
// Fused per-bucket kernel v4: LDS CSR -> gather-mean (quad-owns-node: no
// cross-lane reduce, 16 loads in flight/wave) -> 32x32x16 MFMA GEMM (B and
// root-A frags direct from global, 1-deep prefetch). Epilogue: store (+bf16
// optional) + exact fp32 BN stats -> 16-slice global atomics.
// ---------------------------------------------------------------------------
template <int WRITE_BF16>
__global__ __launch_bounds__(512) void agg_gemm(
    const uint* __restrict__ ebuf, const int* __restrict__ bcursor,
    const u16* __restrict__ X,
    const u16* __restrict__ WtL, const u16* __restrict__ WtR,
    const float* __restrict__ bias,
    float* __restrict__ outf, u16* __restrict__ outb,
    float* __restrict__ gstats) {
    __shared__ u16 Aagg[64][136];        // 17408 B
    __shared__ uint eL[BCAP];            // 8192 B
    __shared__ u16 srcL[BCAP];           // 4096 B
    __shared__ int cnt[64], ro[65], cur[64];
    __shared__ float s1L[128], s2L[128];

    int b = blockIdx.x;
    int t = threadIdx.x;
    int row0 = b * 64;
    int wave = t >> 6, lane = t & 63;
    int quad = lane >> 4, sub = lane & 15;

    // ---- bucket-local CSR in LDS
    int n = bcursor[b];                  // count (cursor was zero-based)
    if (n > BCAP) n = BCAP;
    if (t < 64) cnt[t] = 0;
    if (t < 128) { s1L[t] = 0.f; s2L[t] = 0.f; }
    __syncthreads();
    for (int i = t; i < n; i += 512) {
        uint p = ebuf[b * BSTRIDE + i];
        eL[i] = p;
        atomicAdd(&cnt[p >> 16], 1);
    }
    __syncthreads();
    if (t < 64) {
        int v = cnt[t];
        int s = v;
        #pragma unroll
        for (int off = 1; off < 64; off <<= 1) {
            int u = __shfl_up(s, off, 64);
            if (t >= off) s += u;
        }
        ro[t] = s - v;
        cur[t] = s - v;
        if (t == 63) ro[64] = s;
    }
    __syncthreads();
    for (int i = t; i < n; i += 512) {
        uint p = eL[i];
        int pos = atomicAdd(&cur[p >> 16], 1);
        srcL[pos] = (u16)(p & 0xFFFFu);
    }
    __syncthreads();

    // ---- gather-mean: each quad owns 2 nodes outright (no cross-lane reduce)
    int nl0 = (wave * 4 + quad) * 2;
    #pragma unroll
    for (int g = 0; g < 2; ++g) {
        int nl = nl0 + g;
        int rb = ro[nl], re = ro[nl + 1];
        float a0 = 0.f, a1 = 0.f, a2 = 0.f, a3 = 0.f;
        float a4 = 0.f, a5 = 0.f, a6 = 0.f, a7 = 0.f;
        int e = rb;
        for (; e + 4 <= re; e += 4) {     // 4 independent row-loads in flight
            int s0 = srcL[e], s1 = srcL[e + 1], s2 = srcL[e + 2], s3 = srcL[e + 3];
            uint4 v0 = ((const uint4*)(X + (size_t)s0 * 128))[sub];
            uint4 v1 = ((const uint4*)(X + (size_t)s1 * 128))[sub];
            uint4 v2 = ((const uint4*)(X + (size_t)s2 * 128))[sub];
            uint4 v3 = ((const uint4*)(X + (size_t)s3 * 128))[sub];
            a0 += (bflo(v0.x) + bflo(v1.x)) + (bflo(v2.x) + bflo(v3.x));
            a1 += (bfhi(v0.x) + bfhi(v1.x)) + (bfhi(v2.x) + bfhi(v3.x));
            a2 += (bflo(v0.y) + bflo(v1.y)) + (bflo(v2.y) + bflo(v3.y));
            a3 += (bfhi(v0.y) + bfhi(v1.y)) + (bfhi(v2.y) + bfhi(v3.y));
            a4 += (bflo(v0.z) + bflo(v1.z)) + (bflo(v2.z) + bflo(v3.z));
            a5 += (bfhi(v0.z) + bfhi(v1.z)) + (bfhi(v2.z) + bfhi(v3.z));
            a6 += (bflo(v0.w) + bflo(v1.w)) + (bflo(v2.w) + bflo(v3.w));
            a7 += (bfhi(v0.w) + bfhi(v1.w)) + (bfhi(v2.w) + bfhi(v3.w));
        }
        for (; e < re; ++e) {
            uint4 v0 = ((const uint4*)(X + (size_t)srcL[e] * 128))[sub];
            a0 += bflo(v0.x); a1 += bfhi(v0.x);
            a2 += bflo(v0.y); a3 += bfhi(v0.y);
            a4 += bflo(v0.z); a5 += bfhi(v0.z);
            a6 += bflo(v0.w); a7 += bfhi(v0.w);
        }
        float inv = 1.0f / fmaxf((float)(re - rb), 1.0f);
        uint4 o;
        o.x = pack2(a0 * inv, a1 * inv);
        o.y = pack2(a2 * inv, a3 * inv);
        o.z = pack2(a4 * inv, a5 * inv);
        o.w = pack2(a6 * inv, a7 * inv);
        *(uint4*)&Aagg[nl][sub * 8] = o;
    }
    __syncthreads();   // Aagg complete

    // ---- dual GEMM, 32x32x16 MFMA; wave -> rows rm..rm+31, cols cn..cn+31
    int m31 = lane & 31;
    int kh  = lane >> 5;          // k-half: elems k = ks*16 + kh*8 + j
    int rm = (wave & 1) * 32;
    int cn = (wave >> 1) * 32;
    f16v acc = (f16v)0.f;

    // phase 0: Aagg (LDS) x WtL (global, L2-hot), 1-deep prefetch
    {
        s8 a_nxt = *(const s8*)&Aagg[rm + m31][kh * 8];
        s8 b_nxt = *(const s8*)(WtL + (cn + m31) * 128 + kh * 8);
        #pragma unroll
        for (int ks = 0; ks < 8; ++ks) {
            s8 a_cur = a_nxt, b_cur = b_nxt;
            if (ks < 7) {
                a_nxt = *(const s8*)&Aagg[rm + m31][(ks + 1) * 16 + kh * 8];
                b_nxt = *(const s8*)(WtL + (cn + m31) * 128 + (ks + 1) * 16 + kh * 8);
            }
            acc = __builtin_amdgcn_mfma_f32_32x32x16_bf16(a_cur, b_cur, acc, 0, 0, 0);
        }
    }
    // phase 1: root rows of X (global) x WtR (global)
    {
        const u16* xrow = X + (size_t)(row0 + rm + m31) * 128;
        s8 a_nxt = *(const s8*)(xrow + kh * 8);
        s8 b_nxt = *(const s8*)(WtR + (cn + m31) * 128 + kh * 8);
        #pragma unroll
        for (int ks = 0; ks < 8; ++ks) {
            s8 a_cur = a_nxt, b_cur = b_nxt;
            if (ks < 7) {
                a_nxt = *(const s8*)(xrow + (ks + 1) * 16 + kh * 8);
                b_nxt = *(const s8*)(WtR + (cn + m31) * 128 + (ks + 1) * 16 + kh * 8);
            }
            acc = __builtin_amdgcn_mfma_f32_32x32x16_bf16(a_cur, b_cur, acc, 0, 0, 0);
        }
    }

    // ---- epilogue: store + BN partial stats
    // C/D 32x32: col=lane&31, row=(reg&3)+8*(reg>>2)+4*(lane>>5)  [m74/m101]
    {
        int col = cn + m31;
        float bv = bias[col];
        float s1 = 0.f, s2 = 0.f;
        #pragma unroll
        for (int reg = 0; reg < 16; ++reg) {
            int rowin = (reg & 3) + 8 * (reg >> 2) + 4 * kh;
            int row = row0 + rm + rowin;
            if (row < N_NODES) {
                float v = acc[reg] + bv;
                if (WRITE_BF16)
                    outb[(size_t)row * 128 + col] = f2bf(v);
                else
                    outf[(size_t)row * 128 + col] = v;
                s1 += v;
                s2 = fmaf(v, v, s2);
            }
        }
        s1 += __shfl_xor(s1, 32, 64);
        s2 += __shfl_xor(s2, 32, 64);
        if (lane < 32) {
            atomicAdd(&s1L[col], s1);
            atomicAdd(&s2L[col], s2);
        }
    }
    __syncthreads();
    int slice = b & (NSLICE - 1);
    if (t < 128) {
        atomicAdd(&gstats[slice * 256 + t], s1L[t]);
        atomicAdd(&gstats[slice * 256 + 128 + t], s2L[t]);
    }
}

// ---------------------------------------------------------------------------
// BN(+ReLU) in-place on raw bf16 h (layer-0 -> layer-1 handoff).
// ---------------------------------------------------------------------------
__global__ void bn_relu_inplace(u16* __restrict__ hb,
                                const float* __restrict__ gstats,
                                const float* __restrict__ gamma,
                                const float* __restrict__ beta,
                                float inv_n, int totalv) {   // totalv = N_NODES*16 (uint4s)
    __shared__ float ss[256];
    int t = threadIdx.x;
    if (t < 128) {
        float m = 0.f, q = 0.f;
        #pragma unroll
        for (int s = 0; s < NSLICE; ++s) {
            m += gstats[s * 256 + t];
            q += gstats[s * 256 + 128 + t];
        }
        float mean = m * inv_n;
        float var = q * inv_n - mean * mean;
        float inv = 1.0f / sqrtf(var + BN_EPS);
        float sc = gamma[t] * inv;
        ss[t] = sc;
        ss[128 + t] = beta[t] - mean * sc;
    }
    __syncthreads();
    for (int i = blockIdx.x * 256 + t; i < totalv; i += gridDim.x * 256) {
        int cg = (i & 15) * 8;   // first col of this 8-col group
        uint4 p = ((const uint4*)hb)[i];
        float4 scA = *(const float4*)&ss[cg];
        float4 scB = *(const float4*)&ss[cg + 4];
        float4 shA = *(const float4*)&ss[128 + cg];
        float4 shB = *(const float4*)&ss[128 + cg + 4];
        float r0 = fmaxf(fmaf(bflo(p.x), scA.x, shA.x), 0.f);
        float r1 = fmaxf(fmaf(bfhi(p.x), scA.y, shA.y), 0.f);
        float r2 = fmaxf(fmaf(bflo(p.y), scA.z, shA.z), 0.f);
        float r3 = fmaxf(fmaf(bfhi(p.y), scA.w, shA.w), 0.f);
        float r4 = fmaxf(fmaf(bflo(p.z), scB.x, shB.x), 0.f);
        float r5 = fmaxf(fmaf(bfhi(p.z), scB.y, shB.y), 0.f);
        float r6 = fmaxf(fmaf(bflo(p.w), scB.z, shB.z), 0.f);
        float r7 = fmaxf(fmaf(bfhi(p.w), scB.w, shB.w), 0.f);
        uint4 o;
        o.x = pack2(r0, r1);
        o.y = pack2(r2, r3);
        o.z = pack2(r4, r5);
        o.w = pack2(r6, r7);
        ((uint4*)hb)[i] = o;
    }
}

// final BN, fp32 in-place on d_out
__global__ void bn_apply_kernel(float* __restrict__ h,
                                const float* __restrict__ gstats,
                                const float* __restrict__ gamma,
                                const float* __restrict__ beta,
                                float inv_n, int total4) {
    __shared__ float ss[256];
    int t = threadIdx.x;
    if (t < 128) {
        float m = 0.f, q = 0.f;
        #pragma unroll
        for (int s = 0; s < NSLICE; ++s) {
            m += gstats[s * 256 + t];
            q += gstats[s * 256 + 128 + t];
        }
        float mean = m * inv_n;
        float var = q * inv_n - mean * mean;
        float inv = 1.0f / sqrtf(var + BN_EPS);
        float sc = gamma[t] * inv;
        ss[t] = sc;
        ss[128 + t] = beta[t] - mean * sc;
    }
    __syncthreads();
    for (int i = blockIdx.x * 256 + t; i < total4; i += gridDim.x * 256) {
        int cg = i & 31;
        float4 v = ((float4*)h)[i];
        float4 sc = *(const float4*)&ss[cg * 4];
        float4 sh = *(const float4*)&ss[128 + cg * 4];
        v.x = fmaf(v.x, sc.x, sh.x);
        v.y = fmaf(v.y, sc.y, sh.y);
        v.z = fmaf(v.z, sc.z, sh.z);
        v.w = fmaf(v.w, sc.w, sh.w);
        ((float4*)h)[i] = v;
    }
}

// ---------------------------------------------------------------------------
extern "C" void kernel_launch(void* const* d_in, const int* in_sizes, int n_in,
                              void* d_out, int out_size, void* d_ws, size_t ws_size,
                              hipStream_t stream) {
    const float* x      = (const float*)d_in[0];
    const int*   ei     = (const int*)d_in[1];
    const float* W_l0   = (const float*)d_in[2];
    const float* b_l0   = (const float*)d_in[3];
    const float* W_r0   = (const float*)d_in[4];
    const float* gamma0 = (const float*)d_in[5];
    const float* beta0  = (const float*)d_in[6];
    const float* W_l1   = (const float*)d_in[7];
    const float* b_l1   = (const float*)d_in[8];
    const float* W_r1   = (const float*)d_in[9];
    const float* gamma1 = (const float*)d_in[10];
    const float* beta1  = (const float*)d_in[11];

    const int* src = ei;
    const int* dst = ei + N_EDGES;

    char* w = (char*)d_ws;
    auto alloc = [&](size_t bytes) {
        void* p = (void*)w;
        w += (bytes + 255) & ~(size_t)255;
        return p;
    };
    // zero-init span: gstats0, gstats1, bcursor contiguous
    char* zbase    = w;
    float* gstats0 = (float*)alloc(sizeof(float) * NSLICE * 256);
    float* gstats1 = (float*)alloc(sizeof(float) * NSLICE * 256);
    int* bcursor   = (int*)alloc(sizeof(int) * BUCKS);
    size_t zbytes  = (size_t)(w - zbase);

    uint* ebuf     = (uint*)alloc(sizeof(uint) * BUCKS * BSTRIDE);
    u16* xb        = (u16*)alloc(sizeof(u16) * (size_t)NPAD * 128);
    u16* hb        = (u16*)alloc(sizeof(u16) * (size_t)NPAD * 128);
    u16* Wt        = (u16*)alloc(sizeof(u16) * 4 * 16384);
    float* outp    = (float*)d_out;

    hipMemsetAsync(zbase, 0, zbytes, stream);

    const float inv_n = 1.0f / (float)N_NODES;
    const int total4 = N_NODES * HID / 4;
    const int totalv = N_NODES * HID / 8;
    const int castN = NPAD * 128 + 4 * 16384;

    bucket_scatter_blk<<<(N_EDGES + 8191) / 8192, 1024, 0, stream>>>(src, dst, bcursor, ebuf);
    cast_all<<<(castN + 255) / 256, 256, 0, stream>>>(x, W_l0, W_r0, W_l1, W_r1, xb, Wt);

    // Layer 0: fused agg+gemm+stats, h -> raw bf16 hb
    agg_gemm<1><<<BUCKS, 512, 0, stream>>>(ebuf, bcursor, xb, Wt, Wt + 16384, b_l0,
                                           nullptr, hb, gstats0);
    bn_relu_inplace<<<1024, 256, 0, stream>>>(hb, gstats0, gamma0, beta0, inv_n, totalv);

    // Layer 1: fused agg+gemm+stats, -> fp32 d_out
    agg_gemm<0><<<BUCKS, 512, 0, stream>>>(ebuf, bcursor, hb, Wt + 2 * 16384, Wt + 3 * 16384,
                                           b_l1, outp, nullptr, gstats1);
    bn_apply_kernel<<<2048, 256, 0, stream>>>(outp, gstats1, gamma1, beta1, inv_n, total4);
}